// Round 1
// baseline (255.892 us; speedup 1.0000x reference)
//
#include <hip/hip_runtime.h>
#include <hip/hip_bf16.h>
#include <math.h>

// Problem constants (from reference): N=4096 nodes, D=256 dims, S=32 subspace,
// K=4 heads, ETA=0.5. adj_mask is binary {0,1} with ~2% density + self-loops,
// so masked softmax == sparse softmax over the row's neighbor set
// (exp(-1e9 - max) == 0.0f exactly in fp32).
constexpr int NN = 4096;
constexpr int DD = 256;
constexpr int SS = 32;
constexpr int KK = 4;
constexpr int MAXN = 256;   // max neighbors/row; Binom(4096,.02) mean 82, P(>256) ~ 0
constexpr float ETA = 0.5f;

// ---------------------------------------------------------------------------
// Kernel A: Z[k] = H @ U[k]  ([N,S] per head), Zs = Z * exp(log_precision).
// 32 nodes per block, H tile in LDS, thread (g,k,s) accumulates 16 nodes.
// Also zeroes the loss output slot (runs before orth_loss on the stream).
// ---------------------------------------------------------------------------
__global__ __launch_bounds__(256) void compute_Z(
    const float* __restrict__ H, const float* __restrict__ U,
    const float* __restrict__ lp, float* __restrict__ Z,
    float* __restrict__ Zs, float* __restrict__ loss) {
  __shared__ float Hl[32][DD];   // 32 KB
  const int tid = threadIdx.x;
  const int n0 = blockIdx.x * 32;
  if (blockIdx.x == 0 && tid == 0) loss[0] = 0.0f;

  const float4* H4 = (const float4*)(H + (size_t)n0 * DD);
  float4* Hl4 = (float4*)&Hl[0][0];
  for (int i = tid; i < 32 * DD / 4; i += 256) Hl4[i] = H4[i];
  __syncthreads();

  const int s = tid & 31;
  const int k = (tid >> 5) & 3;
  const int g = tid >> 7;            // 0..1 -> node parity
  float acc[16];
#pragma unroll
  for (int i = 0; i < 16; i++) acc[i] = 0.0f;

  const float* Ucol = U + (size_t)k * DD * SS + s;   // U[k][d][s] = Ucol[d*SS]
  for (int d = 0; d < DD; d++) {
    const float u = Ucol[(size_t)d * SS];
#pragma unroll
    for (int i = 0; i < 16; i++) acc[i] += Hl[2 * i + g][d] * u;  // LDS broadcast
  }

  const float es = expf(lp[k * SS + s]);
#pragma unroll
  for (int i = 0; i < 16; i++) {
    const int n = n0 + 2 * i + g;
    const float z = acc[i];
    Z[((size_t)k * NN + n) * SS + s] = z;
    Zs[((size_t)k * NN + n) * SS + s] = z * es;
  }
}

// ---------------------------------------------------------------------------
// Kernel B: per-row fused mask-scan + sparse attention (all 4 heads) + output.
// One block (256 threads) per row.
// ---------------------------------------------------------------------------
__global__ __launch_bounds__(256) void attn_row(
    const float* __restrict__ H, const float* __restrict__ mask,
    const float* __restrict__ U, const float* __restrict__ thr,
    const float* __restrict__ Z, const float* __restrict__ Zs,
    float* __restrict__ Hout) {
  const int row = blockIdx.x;
  const int tid = threadIdx.x;

  __shared__ int nbr[MAXN];
  __shared__ int cnt;
  __shared__ float Zn[MAXN][SS + 1];  // +1 pad: bank = (p + s) % 32 -> <=2-way (free)
  __shared__ float sc[MAXN];
  __shared__ float w[MAXN];
  __shared__ float zq[SS];
  __shared__ float aggO[KK][SS];
  __shared__ float red[16];

  if (tid == 0) cnt = 0;
  __syncthreads();

  // --- scan this row of the mask, build neighbor index list in LDS ---
  const float4* m4 = (const float4*)(mask + (size_t)row * NN);
  for (int i = tid; i < NN / 4; i += 256) {
    const float4 v = m4[i];
    if (v.x > 0.5f) { int p = atomicAdd(&cnt, 1); if (p < MAXN) nbr[p] = 4 * i; }
    if (v.y > 0.5f) { int p = atomicAdd(&cnt, 1); if (p < MAXN) nbr[p] = 4 * i + 1; }
    if (v.z > 0.5f) { int p = atomicAdd(&cnt, 1); if (p < MAXN) nbr[p] = 4 * i + 2; }
    if (v.w > 0.5f) { int p = atomicAdd(&cnt, 1); if (p < MAXN) nbr[p] = 4 * i + 3; }
  }
  __syncthreads();
  const int c = min(cnt, MAXN);
  const float inv_sqrt_s = 0.17677669529663687f;  // 1/sqrt(32)
  const int s_ = tid & 31;
  const int ch = tid >> 5;

  for (int k = 0; k < KK; k++) {
    // stage query Zs row and neighbor Z rows into LDS
    if (tid < SS) zq[tid] = Zs[((size_t)k * NN + row) * SS + tid];
    if (tid < c) {
      const float4* zr = (const float4*)(Z + ((size_t)k * NN + nbr[tid]) * SS);
#pragma unroll
      for (int q = 0; q < 8; q++) {
        const float4 v = zr[q];
        Zn[tid][4 * q + 0] = v.x;
        Zn[tid][4 * q + 1] = v.y;
        Zn[tid][4 * q + 2] = v.z;
        Zn[tid][4 * q + 3] = v.w;
      }
    }
    __syncthreads();

    // scores: thread p -> dot(zq, Zn[p]) / sqrt(S)
    if (tid < c) {
      float dot = 0.0f;
#pragma unroll
      for (int s = 0; s < SS; s++) dot += zq[s] * Zn[tid][s];
      sc[tid] = dot * inv_sqrt_s;
    }
    __syncthreads();

    // block max
    float v = (tid < c) ? sc[tid] : -3.0e38f;
#pragma unroll
    for (int off = 32; off >= 1; off >>= 1) v = fmaxf(v, __shfl_xor(v, off));
    if ((tid & 63) == 0) red[tid >> 6] = v;
    __syncthreads();
    if (tid == 0) red[8] = fmaxf(fmaxf(red[0], red[1]), fmaxf(red[2], red[3]));
    __syncthreads();
    const float m = red[8];

    // exp + block sum
    const float e = (tid < c) ? expf(sc[tid] - m) : 0.0f;
    w[tid] = e;
    float sv = e;
#pragma unroll
    for (int off = 32; off >= 1; off >>= 1) sv += __shfl_xor(sv, off);
    if ((tid & 63) == 0) red[tid >> 6] = sv;
    __syncthreads();
    if (tid == 0) red[8] = red[0] + red[1] + red[2] + red[3];
    __syncthreads();
    const float invl = 1.0f / red[8];

    // O[s] = invl * sum_p w[p] * Zn[p][s]; thread (ch, s_) does a 32-p chunk
    float o = 0.0f;
    const int pend = min(c, ch * 32 + 32);
    for (int p = ch * 32; p < pend; p++) o += w[p] * Zn[p][s_];
    sc[tid] = o;  // tid == ch*32 + s_ ; sc fully consumed above
    __syncthreads();
    if (tid < SS) {
      float t = 0.0f;
#pragma unroll
      for (int c2 = 0; c2 < 8; c2++) t += sc[c2 * 32 + tid];
      aggO[k][tid] = t * invl;
    }
    __syncthreads();  // protects zq/Zn/sc/w/red for next head
  }

  // epilogue: agg[d] = sum_{k,s} aggO[k][s] * U[k][d][s];  soft threshold
  const int d = tid;
  float a = 0.0f;
#pragma unroll
  for (int k = 0; k < KK; k++) {
    const float* Ur = U + ((size_t)k * DD + d) * SS;
#pragma unroll
    for (int s = 0; s < SS; s++) a += aggO[k][s] * Ur[s];
  }
  const float h = H[(size_t)row * DD + d] + ETA * a;
  const float ab = fabsf(h) - thr[d];
  Hout[(size_t)row * DD + d] = (ab > 0.0f) ? copysignf(ab, h) : 0.0f;
}

// ---------------------------------------------------------------------------
// Kernel C: orthogonality loss. One block per (k<=l) pair; diag pairs subtract I.
// ---------------------------------------------------------------------------
__global__ __launch_bounds__(256) void orth_loss_kernel(
    const float* __restrict__ U, float* __restrict__ loss) {
  const int pk[10] = {0, 0, 0, 0, 1, 1, 1, 2, 2, 3};
  const int pl[10] = {0, 1, 2, 3, 1, 2, 3, 2, 3, 3};
  const int k = pk[blockIdx.x];
  const int l = pl[blockIdx.x];
  const int tid = threadIdx.x;

  float acc = 0.0f;
  for (int e = tid; e < SS * SS; e += 256) {
    const int a = e >> 5, b = e & 31;
    float cv = 0.0f;
    for (int d = 0; d < DD; d++)
      cv += U[((size_t)k * DD + d) * SS + a] * U[((size_t)l * DD + d) * SS + b];
    if (k == l && a == b) cv -= 1.0f;
    acc += cv * cv;
  }
#pragma unroll
  for (int off = 32; off >= 1; off >>= 1) acc += __shfl_xor(acc, off);
  __shared__ float red[4];
  if ((tid & 63) == 0) red[tid >> 6] = acc;
  __syncthreads();
  if (tid == 0) atomicAdd(loss, red[0] + red[1] + red[2] + red[3]);
}

// ---------------------------------------------------------------------------
extern "C" void kernel_launch(void* const* d_in, const int* in_sizes, int n_in,
                              void* d_out, int out_size, void* d_ws, size_t ws_size,
                              hipStream_t stream) {
  const float* H    = (const float*)d_in[0];
  const float* mask = (const float*)d_in[1];
  const float* U    = (const float*)d_in[2];
  const float* lp   = (const float*)d_in[3];
  const float* thr  = (const float*)d_in[4];

  float* Hout = (float*)d_out;
  float* loss = Hout + (size_t)NN * DD;   // outputs concatenated: [N*D] + [1]

  float* Z  = (float*)d_ws;               // [K][N][S]
  float* Zs = Z + (size_t)KK * NN * SS;   // [K][N][S]  (4 MB total scratch)

  compute_Z<<<NN / 32, 256, 0, stream>>>(H, U, lp, Z, Zs, loss);
  orth_loss_kernel<<<10, 256, 0, stream>>>(U, loss);
  attn_row<<<NN, 256, 0, stream>>>(H, mask, U, thr, Z, Zs, Hout);
}

// Round 3
// 175.881 us; speedup vs baseline: 1.4549x; 1.4549x over previous
//
#include <hip/hip_runtime.h>
#include <math.h>

// N=4096 nodes, D=256, S=32, K=4 heads, ETA=0.5.
// adj_mask is binary {0,1} (~2% density + self-loops): masked softmax ==
// exact sparse softmax over each row's neighbor set (exp(-1e9-max)==0 in fp32).
constexpr int NN = 4096;
constexpr int DD = 256;
constexpr int SS = 32;
constexpr int KK = 4;
constexpr int MAXN = 192;   // neighbors/row: mean 83, sd 9 -> 192 is +12 sd
constexpr float ETA = 0.5f;

// Compiler-level memory fence: zero instructions, forbids reordering of memory
// ops across it (kills any TBAA/hoisting hazard on same-wave LDS RAW edges;
// hardware services a wave's DS ops in issue order).
#define MEMFENCE() __asm__ volatile("" ::: "memory")

// ---------------------------------------------------------------------------
// Kernel 1 (prep): blocks 0..255 compute Z[k] = H @ U[k]  (16 nodes/block);
// blocks 256..265 compute orth-loss partial for one (k<=l) pair -> lossp[pair].
// Block 256 additionally writes elp[k][s] = exp(log_precision[k][s]).
// ---------------------------------------------------------------------------
__global__ __launch_bounds__(256) void prep_kernel(
    const float* __restrict__ H, const float* __restrict__ U,
    const float* __restrict__ lp, float* __restrict__ Z,
    float* __restrict__ elp, float* __restrict__ lossp) {
  __shared__ float Hl[16][DD];   // 16 KB (Z path only)
  __shared__ float red[4];
  const int tid = threadIdx.x;

  if (blockIdx.x < 256) {
    // ---- Z path: 16 nodes per block ----
    const int n0 = blockIdx.x * 16;
    const float4* H4 = (const float4*)(H + (size_t)n0 * DD);
    float4* Hl4 = (float4*)&Hl[0][0];
    for (int i = tid; i < 16 * DD / 4; i += 256) Hl4[i] = H4[i];
    __syncthreads();

    const int s = tid & 31;
    const int k = (tid >> 5) & 3;
    const int g = tid >> 7;          // node parity
    float acc[8];
#pragma unroll
    for (int i = 0; i < 8; i++) acc[i] = 0.0f;

    const float* Ucol = U + (size_t)k * DD * SS + s;  // U[k][d][s] at Ucol[d*SS]
    for (int d = 0; d < DD; d++) {
      const float u = Ucol[(size_t)d * SS];
#pragma unroll
      for (int i = 0; i < 8; i++) acc[i] += Hl[2 * i + g][d] * u;  // LDS broadcast
    }
#pragma unroll
    for (int i = 0; i < 8; i++) {
      const int n = n0 + 2 * i + g;
      Z[((size_t)k * NN + n) * SS + s] = acc[i];
    }
  } else {
    // ---- orth path: one (k<=l) pair per block, 4 ILP chains per thread ----
    const int pair = blockIdx.x - 256;
    if (pair == 0 && tid < KK * SS) elp[tid] = expf(lp[tid]);
    const int pk[10] = {0, 0, 0, 0, 1, 1, 1, 2, 2, 3};
    const int pl[10] = {0, 1, 2, 3, 1, 2, 3, 2, 3, 3};
    const int k = pk[pair], l = pl[pair];
    const int b = tid & 31;
    const int a0 = tid >> 5;         // cell a = a0 + 8*j
    float acc[4] = {0.f, 0.f, 0.f, 0.f};
    for (int d = 0; d < DD; d++) {
      const float ub = U[((size_t)l * DD + d) * SS + b];
#pragma unroll
      for (int j = 0; j < 4; j++)
        acc[j] += U[((size_t)k * DD + d) * SS + a0 + 8 * j] * ub;
    }
    float tot = 0.f;
#pragma unroll
    for (int j = 0; j < 4; j++) {
      const float cv = acc[j] - ((k == l && (a0 + 8 * j) == b) ? 1.0f : 0.0f);
      tot += cv * cv;
    }
#pragma unroll
    for (int off = 32; off >= 1; off >>= 1) tot += __shfl_xor(tot, off);
    if ((tid & 63) == 0) red[tid >> 6] = tot;
    __syncthreads();
    if (tid == 0) lossp[pair] = red[0] + red[1] + red[2] + red[3];
  }
}

// ---------------------------------------------------------------------------
// Kernel 2: wave-per-row sparse attention, 4 rows/block.
// Scan: deterministic ballot/popcount compaction (count stays in registers).
// Phase A: query loaded from GLOBAL Z row (broadcast) * elp; wave-shuffle softmax.
// Phase B: weighted V-sum, lane=(p-parity, s); Z rows re-read from L2.
// Epilogue (after the single __syncthreads): U-projection + soft threshold x4 rows.
// ---------------------------------------------------------------------------
__global__ __launch_bounds__(256) void attn_row(
    const float* __restrict__ H, const float* __restrict__ mask,
    const float* __restrict__ U, const float* __restrict__ thr,
    const float* __restrict__ Z, const float* __restrict__ elp,
    const float* __restrict__ lossp, float* __restrict__ Hout,
    float* __restrict__ loss) {
  const int tid = threadIdx.x;
  const int wv = tid >> 6;
  const int lane = tid & 63;
  const int row = blockIdx.x * 4 + wv;

  __shared__ int nbr[4][MAXN];
  __shared__ float wgt[4][MAXN];
  __shared__ float aggO[4][KK][SS];

  if (blockIdx.x == 0 && tid == 0) {
    float t = 0.f;
#pragma unroll
    for (int i = 0; i < 10; i++) t += lossp[i];
    loss[0] = t;
  }

  // --- ballot-based mask-row scan: deterministic compaction, no atomics ---
  const float4* m4 = (const float4*)(mask + (size_t)row * NN);
  const unsigned long long lt = (1ULL << lane) - 1ULL;
  int cnt = 0;  // wave-uniform running count (every lane adds full popcounts)
  for (int i = lane; i < NN / 4; i += 64) {
    const float4 v = m4[i];
    unsigned long long b;
    b = __ballot(v.x > 0.5f);
    if (v.x > 0.5f) { const int p = cnt + (int)__popcll(b & lt); if (p < MAXN) nbr[wv][p] = 4 * i; }
    cnt += (int)__popcll(b);
    b = __ballot(v.y > 0.5f);
    if (v.y > 0.5f) { const int p = cnt + (int)__popcll(b & lt); if (p < MAXN) nbr[wv][p] = 4 * i + 1; }
    cnt += (int)__popcll(b);
    b = __ballot(v.z > 0.5f);
    if (v.z > 0.5f) { const int p = cnt + (int)__popcll(b & lt); if (p < MAXN) nbr[wv][p] = 4 * i + 2; }
    cnt += (int)__popcll(b);
    b = __ballot(v.w > 0.5f);
    if (v.w > 0.5f) { const int p = cnt + (int)__popcll(b & lt); if (p < MAXN) nbr[wv][p] = 4 * i + 3; }
    cnt += (int)__popcll(b);
  }
  const int c = min(cnt, MAXN);
  MEMFENCE();  // nbr writes ordered before all later reads (same wave)

  const float inv_sqrt_s = 0.17677669529663687f;  // 1/sqrt(32)
  const int g = lane >> 5;
  const int s_ = lane & 31;

  for (int k = 0; k < KK; k++) {
    MEMFENCE();
    // query from global (broadcast loads, L1-resident): q = Z[k][row] * exp(lp[k])
    const float4* Zq4 = (const float4*)(Z + ((size_t)k * NN + row) * SS);
    const float4* E4 = (const float4*)(elp + k * SS);
    float4 q[8];
#pragma unroll
    for (int u = 0; u < 8; u++) {
      const float4 a = Zq4[u];
      const float4 e = E4[u];
      q[u].x = a.x * e.x; q[u].y = a.y * e.y; q[u].z = a.z * e.z; q[u].w = a.w * e.w;
    }

    // --- Phase A: scores for up to 3 neighbors per lane ---
    float scl[3];
#pragma unroll
    for (int t = 0; t < 3; t++) {
      const int p = lane + t * 64;
      float dot = -3.0e38f;
      if (p < c) {
        const float4* zr = (const float4*)(Z + ((size_t)k * NN + nbr[wv][p]) * SS);
        float dd = 0.f;
#pragma unroll
        for (int u = 0; u < 8; u++) {
          const float4 v = zr[u];
          dd += v.x * q[u].x + v.y * q[u].y + v.z * q[u].z + v.w * q[u].w;
        }
        dot = dd * inv_sqrt_s;
      }
      scl[t] = dot;
    }
    // wave softmax (64-lane butterflies)
    float mx = fmaxf(scl[0], fmaxf(scl[1], scl[2]));
#pragma unroll
    for (int off = 32; off >= 1; off >>= 1) mx = fmaxf(mx, __shfl_xor(mx, off));
    float e[3];
    float sv = 0.f;
#pragma unroll
    for (int t = 0; t < 3; t++) { e[t] = expf(scl[t] - mx); sv += e[t]; }  // invalid -> 0
#pragma unroll
    for (int off = 32; off >= 1; off >>= 1) sv += __shfl_xor(sv, off);
    const float invl = 1.0f / sv;
#pragma unroll
    for (int t = 0; t < 3; t++) {
      const int p = lane + t * 64;
      if (p < c) wgt[wv][p] = e[t] * invl;
    }
    MEMFENCE();  // wgt writes ordered before Phase B reads (same wave)

    // --- Phase B: O[s] = sum_p wgt[p] * Z[k][nbr[p]][s]; lane=(g,s_) ---
    const float* Zk = Z + (size_t)k * NN * SS;
    float o0 = 0.f, o1 = 0.f;
    int p = g;
    for (; p + 2 < c; p += 4) {
      o0 += wgt[wv][p]     * Zk[(size_t)nbr[wv][p]     * SS + s_];
      o1 += wgt[wv][p + 2] * Zk[(size_t)nbr[wv][p + 2] * SS + s_];
    }
    for (; p < c; p += 2)
      o0 += wgt[wv][p] * Zk[(size_t)nbr[wv][p] * SS + s_];
    float o = o0 + o1;
    o += __shfl_xor(o, 32);  // even-p half + odd-p half, same s_
    if (lane < SS) aggO[wv][k][lane] = o;
    MEMFENCE();
  }

  __syncthreads();

  // --- epilogue: agg[d] = sum_{k,s} aggO[r][k][s]*U[k][d][s], 4 rows at once ---
  const int d = tid;
  const float4* U4 = (const float4*)U;
  float a0 = 0.f, a1 = 0.f, a2 = 0.f, a3 = 0.f;
#pragma unroll
  for (int k = 0; k < KK; k++) {
    const int base = ((k * DD + d) * SS) >> 2;
#pragma unroll
    for (int sq = 0; sq < 8; sq++) {
      const float4 u = U4[base + sq];
      const float uu[4] = {u.x, u.y, u.z, u.w};
#pragma unroll
      for (int j = 0; j < 4; j++) {
        const int s = sq * 4 + j;
        a0 += aggO[0][k][s] * uu[j];
        a1 += aggO[1][k][s] * uu[j];
        a2 += aggO[2][k][s] * uu[j];
        a3 += aggO[3][k][s] * uu[j];
      }
    }
  }
  const float tv = thr[d];
  const int row0 = blockIdx.x * 4;
  const float ar[4] = {a0, a1, a2, a3};
#pragma unroll
  for (int r = 0; r < 4; r++) {
    const float h = H[(size_t)(row0 + r) * DD + d] + ETA * ar[r];
    const float ab = fabsf(h) - tv;
    Hout[(size_t)(row0 + r) * DD + d] = (ab > 0.0f) ? copysignf(ab, h) : 0.0f;
  }
}

// ---------------------------------------------------------------------------
extern "C" void kernel_launch(void* const* d_in, const int* in_sizes, int n_in,
                              void* d_out, int out_size, void* d_ws, size_t ws_size,
                              hipStream_t stream) {
  const float* H    = (const float*)d_in[0];
  const float* mask = (const float*)d_in[1];
  const float* U    = (const float*)d_in[2];
  const float* lp   = (const float*)d_in[3];
  const float* thr  = (const float*)d_in[4];

  float* Hout = (float*)d_out;
  float* loss = Hout + (size_t)NN * DD;    // outputs concatenated: [N*D] + [1]

  float* Z     = (float*)d_ws;              // [K][N][S], 2 MB, 16B-aligned
  float* elp   = Z + (size_t)KK * NN * SS;  // [K][S] = 128 floats, 16B-aligned
  float* lossp = elp + KK * SS;             // [10]

  prep_kernel<<<266, 256, 0, stream>>>(H, U, lp, Z, elp, lossp);
  attn_row<<<NN / 4, 256, 0, stream>>>(H, mask, U, thr, Z, elp, lossp, Hout, loss);
}

// Round 4
// 168.247 us; speedup vs baseline: 1.5209x; 1.0454x over previous
//
#include <hip/hip_runtime.h>
#include <math.h>

// N=4096 nodes, D=256, S=32, K=4 heads, ETA=0.5.
// adj_mask is binary {0,1} (~2% density + self-loops): masked softmax ==
// exact sparse softmax over each row's neighbor set (exp(-1e9-max)==0 in fp32).
constexpr int NN = 4096;
constexpr int DD = 256;
constexpr int SS = 32;
constexpr int KK = 4;
constexpr int MAXN = 192;    // row degree: mean 83, sd 9 -> 192 = +12 sd
constexpr int SEGMAX = 96;   // per-quarter-row degree: mean ~21, sd 4.5
constexpr float ETA = 0.5f;

#define MEMFENCE() __asm__ volatile("" ::: "memory")

// ---------------------------------------------------------------------------
// Kernel 1 (prep):
//   blocks [0,1024):  Z[k] = H @ U[k]; block b -> head k=b&3, nodes (b>>2)*16..+16
//   blocks [1024,1034): orth-loss partial for one (k<=l) pair -> lossp[pair];
//                       pair 0 also writes elp = exp(log_precision).
// ---------------------------------------------------------------------------
__global__ __launch_bounds__(256) void prep_kernel(
    const float* __restrict__ H, const float* __restrict__ U,
    const float* __restrict__ lp, float* __restrict__ Z,
    float* __restrict__ elp, float* __restrict__ lossp) {
  __shared__ float Hl[16][DD];   // 16 KB (Z path only)
  __shared__ float red[4];
  const int tid = threadIdx.x;

  if (blockIdx.x < 1024) {
    const int k = blockIdx.x & 3;
    const int n0 = (blockIdx.x >> 2) * 16;

    const float4* H4 = (const float4*)(H + (size_t)n0 * DD);
    float4* Hl4 = (float4*)&Hl[0][0];
    for (int i = tid; i < 16 * DD / 4; i += 256) Hl4[i] = H4[i];
    __syncthreads();

    const int s = tid & 31;
    const int n_l = (tid >> 5) & 7;   // 0..7; thread owns nodes n_l and n_l+8
    const float* Uk = U + (size_t)k * DD * SS;
    float acc0 = 0.f, acc1 = 0.f;
#pragma unroll 4
    for (int dq = 0; dq < DD / 4; dq++) {
      const float4 h0 = Hl4[n_l * (DD / 4) + dq];        // LDS broadcast b128
      const float4 h1 = Hl4[(n_l + 8) * (DD / 4) + dq];
      const float u0 = Uk[(4 * dq + 0) * SS + s];        // coalesced 128B
      const float u1 = Uk[(4 * dq + 1) * SS + s];
      const float u2 = Uk[(4 * dq + 2) * SS + s];
      const float u3 = Uk[(4 * dq + 3) * SS + s];
      acc0 += h0.x * u0 + h0.y * u1 + h0.z * u2 + h0.w * u3;
      acc1 += h1.x * u0 + h1.y * u1 + h1.z * u2 + h1.w * u3;
    }
    Z[((size_t)k * NN + n0 + n_l) * SS + s] = acc0;
    Z[((size_t)k * NN + n0 + n_l + 8) * SS + s] = acc1;
  } else {
    // ---- orth path: one (k<=l) pair per block ----
    const int pair = blockIdx.x - 1024;
    if (pair == 0 && tid < KK * SS) elp[tid] = expf(lp[tid]);
    const int pk[10] = {0, 0, 0, 0, 1, 1, 1, 2, 2, 3};
    const int pl[10] = {0, 1, 2, 3, 1, 2, 3, 2, 3, 3};
    const int k = pk[pair], l = pl[pair];
    const int b = tid & 31;
    const int a0 = tid >> 5;          // cell a = a0 + 8*j
    float acc[4] = {0.f, 0.f, 0.f, 0.f};
    for (int d = 0; d < DD; d++) {
      const float ub = U[((size_t)l * DD + d) * SS + b];
#pragma unroll
      for (int j = 0; j < 4; j++)
        acc[j] += U[((size_t)k * DD + d) * SS + a0 + 8 * j] * ub;
    }
    float tot = 0.f;
#pragma unroll
    for (int j = 0; j < 4; j++) {
      const float cv = acc[j] - ((k == l && (a0 + 8 * j) == b) ? 1.0f : 0.0f);
      tot += cv * cv;
    }
#pragma unroll
    for (int off = 32; off >= 1; off >>= 1) tot += __shfl_xor(tot, off);
    if ((tid & 63) == 0) red[tid >> 6] = tot;
    __syncthreads();
    if (tid == 0) lossp[pair] = red[0] + red[1] + red[2] + red[3];
  }
}

// ---------------------------------------------------------------------------
// Kernel 2: one ROW per block, one HEAD per wave (4 waves).
//   Scan: each wave ballot-compacts its quarter of the mask row (4 iters).
//   Merge: prefix over 4 segment counts -> packed nbr[] list.
//   Flash head (wave k): lane=(p_sub in [0,8), sq in [0,8)); each neighbor Z
//   row is read ONCE as float4; dot via 3 shuffles; online-softmax rescale;
//   O accumulated in registers; result written straight to global AO[row][k*32..].
// ---------------------------------------------------------------------------
__global__ __launch_bounds__(256) void attn_row(
    const float* __restrict__ mask, const float* __restrict__ Z,
    const float* __restrict__ elp, const float* __restrict__ lossp,
    float* __restrict__ AO, float* __restrict__ loss) {
  const int tid = threadIdx.x;
  const int wv = tid >> 6;
  const int lane = tid & 63;
  const int row = blockIdx.x;

  __shared__ int segn[4][SEGMAX];
  __shared__ int segc[4];
  __shared__ int nbr[MAXN];

  if (blockIdx.x == 0 && tid == 0) {
    float t = 0.f;
#pragma unroll
    for (int i = 0; i < 10; i++) t += lossp[i];
    loss[0] = t;
  }

  // --- scan: wave wv covers float4 indices [wv*256, wv*256+256) of the row ---
  const float4* m4 = (const float4*)(mask + (size_t)row * NN);
  const unsigned long long lt = (1ULL << lane) - 1ULL;
  int cnt = 0;
#pragma unroll
  for (int it = 0; it < 4; it++) {
    const int i = wv * 256 + it * 64 + lane;   // coalesced within wave
    const float4 v = m4[i];
    unsigned long long b;
    b = __ballot(v.x > 0.5f);
    if (v.x > 0.5f) { const int p = cnt + (int)__popcll(b & lt); if (p < SEGMAX) segn[wv][p] = 4 * i; }
    cnt += (int)__popcll(b);
    b = __ballot(v.y > 0.5f);
    if (v.y > 0.5f) { const int p = cnt + (int)__popcll(b & lt); if (p < SEGMAX) segn[wv][p] = 4 * i + 1; }
    cnt += (int)__popcll(b);
    b = __ballot(v.z > 0.5f);
    if (v.z > 0.5f) { const int p = cnt + (int)__popcll(b & lt); if (p < SEGMAX) segn[wv][p] = 4 * i + 2; }
    cnt += (int)__popcll(b);
    b = __ballot(v.w > 0.5f);
    if (v.w > 0.5f) { const int p = cnt + (int)__popcll(b & lt); if (p < SEGMAX) segn[wv][p] = 4 * i + 3; }
    cnt += (int)__popcll(b);
  }
  if (lane == 0) segc[wv] = min(cnt, SEGMAX);
  MEMFENCE();
  __syncthreads();

  // --- merge segments into packed nbr[] ---
  const int c0 = segc[0], c1 = segc[1], c2 = segc[2], c3 = segc[3];
  const int offs[4] = {0, c0, c0 + c1, c0 + c1 + c2};
  const int c = min(c0 + c1 + c2 + c3, MAXN);
  const int myc = segc[wv];
  const int myoff = offs[wv];
  for (int i = lane; i < myc; i += 64) {
    const int p = myoff + i;
    if (p < MAXN) nbr[p] = segn[wv][i];
  }
  MEMFENCE();
  __syncthreads();

  // --- flash head: k = wv ---
  const int k = wv;
  const int p_sub = lane >> 3;   // 0..7  (neighbor within chunk)
  const int sq = lane & 7;       // 0..7  (float4 slice of the 32-dim row)
  const float inv_sqrt_s = 0.17677669529663687f;  // 1/sqrt(32)

  // query quad: q4 = Z[k][row][4sq..4sq+3] * exp(lp[k][...])
  const float4* Zq4 = (const float4*)(Z + ((size_t)k * NN + row) * SS);
  const float4* E4 = (const float4*)(elp + k * SS);
  float4 q4;
  {
    const float4 a = Zq4[sq], e = E4[sq];
    q4.x = a.x * e.x; q4.y = a.y * e.y; q4.z = a.z * e.z; q4.w = a.w * e.w;
  }

  float m = -3.0e38f, l = 0.f;
  float4 oacc = {0.f, 0.f, 0.f, 0.f};
  const float* Zk = Z + (size_t)k * NN * SS;

  for (int p0 = 0; p0 < c; p0 += 8) {
    const int p = p0 + p_sub;
    const bool act = p < c;
    float4 z4 = {0.f, 0.f, 0.f, 0.f};
    if (act) z4 = ((const float4*)(Zk + (size_t)nbr[p] * SS))[sq];
    float dot = q4.x * z4.x + q4.y * z4.y + q4.z * z4.z + q4.w * z4.w;
    dot += __shfl_xor(dot, 1);
    dot += __shfl_xor(dot, 2);
    dot += __shfl_xor(dot, 4);       // full dot, uniform across sq group
    dot *= inv_sqrt_s;
    if (!act) dot = -3.0e38f;
    // chunk max over the 8 p_subs (wave-uniform)
    float cm = dot;
    cm = fmaxf(cm, __shfl_xor(cm, 8));
    cm = fmaxf(cm, __shfl_xor(cm, 16));
    cm = fmaxf(cm, __shfl_xor(cm, 32));
    const float mn = fmaxf(m, cm);
    const float alpha = __expf(m - mn);     // 0 on first chunk (m=-3e38)
    const float w = __expf(dot - mn);       // 0 for inactive lanes
    float ws = w;
    ws += __shfl_xor(ws, 8);
    ws += __shfl_xor(ws, 16);
    ws += __shfl_xor(ws, 32);               // sum of the 8 distinct w's
    l = l * alpha + ws;
    oacc.x = oacc.x * alpha + w * z4.x;
    oacc.y = oacc.y * alpha + w * z4.y;
    oacc.z = oacc.z * alpha + w * z4.z;
    oacc.w = oacc.w * alpha + w * z4.w;
    m = mn;
  }
  // reduce O over p_sub groups
#pragma unroll
  for (int off = 8; off <= 32; off <<= 1) {
    oacc.x += __shfl_xor(oacc.x, off);
    oacc.y += __shfl_xor(oacc.y, off);
    oacc.z += __shfl_xor(oacc.z, off);
    oacc.w += __shfl_xor(oacc.w, off);
  }
  const float invl = 1.0f / l;   // l wave-uniform; c>=1 (self-loop) so l>0
  if (p_sub == 0) {
    float4 o;
    o.x = oacc.x * invl; o.y = oacc.y * invl; o.z = oacc.z * invl; o.w = oacc.w * invl;
    ((float4*)AO)[(size_t)row * (KK * SS / 4) + k * 8 + sq] = o;  // 128B/wave store
  }
}

// ---------------------------------------------------------------------------
// Kernel 3 (epilogue): Hout = softthresh(H + ETA * AO @ Ufl), Ufl[(k,s)][d]=U[k][d][s].
// 4 rows per block, 1024 blocks; d = tid; AO tile staged in LDS.
// ---------------------------------------------------------------------------
__global__ __launch_bounds__(256) void epilogue_kernel(
    const float* __restrict__ H, const float* __restrict__ U,
    const float* __restrict__ thr, const float* __restrict__ AO,
    float* __restrict__ Hout) {
  __shared__ float AOl[4][KK * SS];   // 2 KB
  const int tid = threadIdx.x;
  const int r0 = blockIdx.x * 4;

  const float4* AO4 = (const float4*)(AO + (size_t)r0 * KK * SS);
  float4* AOl4 = (float4*)&AOl[0][0];
  if (tid < 128) AOl4[tid] = AO4[tid];
  __syncthreads();

  const int d = tid;
  float acc[4] = {0.f, 0.f, 0.f, 0.f};
  const float4* U4 = (const float4*)U;
#pragma unroll
  for (int k = 0; k < KK; k++) {
    const int ubase = (k * DD + d) * (SS / 4);
#pragma unroll
    for (int sq = 0; sq < SS / 4; sq++) {
      const float4 u = U4[ubase + sq];   // thread-contiguous 128B row of U[k][d][:]
#pragma unroll
      for (int r = 0; r < 4; r++) {
        const float4 a = AOl4[r * (KK * SS / 4) + k * (SS / 4) + sq];  // LDS b128 broadcast
        acc[r] += u.x * a.x + u.y * a.y + u.z * a.z + u.w * a.w;
      }
    }
  }
  const float tv = thr[d];
#pragma unroll
  for (int r = 0; r < 4; r++) {
    const float h = H[(size_t)(r0 + r) * DD + d] + ETA * acc[r];
    const float ab = fabsf(h) - tv;
    Hout[(size_t)(r0 + r) * DD + d] = (ab > 0.0f) ? copysignf(ab, h) : 0.0f;
  }
}

// ---------------------------------------------------------------------------
extern "C" void kernel_launch(void* const* d_in, const int* in_sizes, int n_in,
                              void* d_out, int out_size, void* d_ws, size_t ws_size,
                              hipStream_t stream) {
  const float* H    = (const float*)d_in[0];
  const float* mask = (const float*)d_in[1];
  const float* U    = (const float*)d_in[2];
  const float* lp   = (const float*)d_in[3];
  const float* thr  = (const float*)d_in[4];

  float* Hout = (float*)d_out;
  float* loss = Hout + (size_t)NN * DD;      // outputs: [N*D] + [1]

  float* Z     = (float*)d_ws;               // [K][N][S]   2 MB (16B aligned)
  float* AO    = Z + (size_t)KK * NN * SS;   // [N][K*S]    2 MB (16B aligned)
  float* elp   = AO + (size_t)NN * KK * SS;  // [K*S]       (16B aligned)
  float* lossp = elp + KK * SS;              // [10]

  prep_kernel<<<1034, 256, 0, stream>>>(H, U, lp, Z, elp, lossp);
  attn_row<<<NN, 256, 0, stream>>>(mask, Z, elp, lossp, AO, loss);
  epilogue_kernel<<<NN / 4, 256, 0, stream>>>(H, U, thr, AO, Hout);
}